// Round 8
// baseline (200.488 us; speedup 1.0000x reference)
//
#include <hip/hip_runtime.h>

#define NPTS  4096
#define MQ    1024
#define BATCH 16
#define KNN   32
#define CIN   64
#define H1D   64
#define H2D   128

typedef _Float16 half8 __attribute__((ext_vector_type(8)));
typedef float    floatx4 __attribute__((ext_vector_type(4)));

#define W1F_HALVES  (3 * 4 * 64 * 8)   // 6144
#define W2F_HALVES  (2 * 8 * 64 * 8)   // 8192
// ws layout: wf [28KB] | pos4 [1MB] | feat16 [8MB]
#define WS_WF_BYTES ((size_t)(W1F_HALVES + W2F_HALVES) * 2)
#define WS_P4_OFF   WS_WF_BYTES
#define WS_F16_OFF  (WS_P4_OFF + (size_t)BATCH * NPTS * 16)
#define WS_NEED     (WS_F16_OFF + (size_t)BATCH * NPTS * CIN * 2)

// ---------------------------------------------------------------------------
// Kernel 0: pack W1/W2 into f16 MFMA B-fragment layout, pack pos into
// float4 {x,y,z,|p|^2} (exact reference association), optionally convert
// feat to f16 (same (_Float16) rounding the MLP pack used before -> MLP
// output bit-identical).
// ---------------------------------------------------------------------------
__global__ __launch_bounds__(256) void wprep_kernel(
    const float* __restrict__ W1, const float* __restrict__ W2,
    const float* __restrict__ pos, const float* __restrict__ feat,
    _Float16* __restrict__ wout, float4* __restrict__ pos4,
    _Float16* __restrict__ feat16, int do_f16)
{
    const int gid = blockIdx.x * 256 + threadIdx.x;
    if (gid < 768) {                                 // W1 fragments
        const int s = gid;
        const int kc = s >> 8, nt = (s >> 6) & 3, lane = s & 63;
        const int col = lane & 15, quad = lane >> 4;
        half8 ph;
#pragma unroll
        for (int j = 0; j < 8; ++j) {
            const int k = kc * 32 + quad * 8 + j;
            ph[j] = (k < 67) ? (_Float16)W1[k * H1D + nt * 16 + col] : (_Float16)0.0f;
        }
        *(half8*)(wout + (size_t)s * 8) = ph;
    } else if (gid < 1792) {                         // W2 fragments
        const int s2 = gid - 768;
        const int kc2 = s2 >> 9, nt2 = (s2 >> 6) & 7, lane = s2 & 63;
        const int col = lane & 15, quad = lane >> 4;
        half8 ph;
#pragma unroll
        for (int j = 0; j < 8; ++j) {
            const int k = kc2 * 32 + quad * 8 + j;
            ph[j] = (_Float16)W2[k * H2D + nt2 * 16 + col];
        }
        *(half8*)(wout + (size_t)W1F_HALVES + (size_t)s2 * 8) = ph;
    } else if (gid < 1792 + BATCH * NPTS) {          // pos4
        const int p = gid - 1792;
        const float px = pos[p * 3 + 0], py = pos[p * 3 + 1], pz = pos[p * 3 + 2];
        float4 v;
        v.x = px; v.y = py; v.z = pz;
        v.w = __fadd_rn(__fadd_rn(__fmul_rn(px, px), __fmul_rn(py, py)),
                        __fmul_rn(pz, pz));
        pos4[p] = v;
    } else if (do_f16) {                             // feat -> f16 (8 ch/thread)
        const int s = gid - (1792 + BATCH * NPTS);
        if (s < BATCH * NPTS * 8) {
            const int row = s >> 3, c8 = (s & 7) * 8;
            const float4* fp = (const float4*)(feat + (size_t)row * CIN + c8);
            const float4 a = fp[0], c = fp[1];
            half8 h;
            h[0] = (_Float16)a.x; h[1] = (_Float16)a.y;
            h[2] = (_Float16)a.z; h[3] = (_Float16)a.w;
            h[4] = (_Float16)c.x; h[5] = (_Float16)c.y;
            h[6] = (_Float16)c.z; h[7] = (_Float16)c.w;
            *(half8*)(feat16 + (size_t)row * CIN + c8) = h;
        }
    }
}

// ---------------------------------------------------------------------------
// Fused kernel: block = 4 queries. Phase 1 = exact KNN for all 4 queries
// (interleaved: each point loaded once, 4 keys; keys in VGPRs; 4 private
// 2048-bin histograms; exact radix-select + lexicographic (key,idx) rank —
// identical selection math to the r2-verified bitwise-exact lineage).
// Phase 2 = r6-verified per-wave f16-MFMA MLP reading neighbors from LDS.
// r8 fix: full 32KB histogram zero-init (r7 only zeroed half -> garbage
// prefixes for queries 2,3 -> LDS OOB -> global OOB fault), plus a
// defensive bound on the definite-member write.
// ---------------------------------------------------------------------------
template<int USE_F16>
__global__ __launch_bounds__(256, 4) void fused_kernel(
    const float4* __restrict__ pos4, const float* __restrict__ feat,
    const _Float16* __restrict__ feat16, const int* __restrict__ idx,
    const float* __restrict__ b1, const float* __restrict__ b2,
    const _Float16* __restrict__ wf,
    float* __restrict__ pos_q, float* __restrict__ out)
{
    __shared__ unsigned int histS[4 * 2048];   // 32 KB; aliased as frag region in phase 2
    __shared__ unsigned int ckeyS[4][64];
    __shared__ int          cidxS[4][64];
    __shared__ int          nnLDS[4][KNN];
    __shared__ unsigned int scS[4][8];         // 0:prefix 1:rank 2:bincnt 3:def 4:cand
    __shared__ unsigned int wsumS[4][4];
    _Float16* sh = (_Float16*)histS;           // phase-2 fragment region (24 KB)

    const int t = threadIdx.x;
    const int w = t >> 6, lane = t & 63;
    const int qblk = blockIdx.x * 4;
    const int b = qblk >> 10;
    const float4* pb4 = pos4 + (size_t)b * NPTS;

    // ---------------- phase 1: KNN ----------------
    float4 qvv[4];
#pragma unroll
    for (int qi = 0; qi < 4; ++qi)
        qvv[qi] = pb4[idx[(size_t)b * MQ + ((qblk & (MQ - 1)) + qi)]];

    {
        int4* hz = (int4*)histS;               // 2048 int4s total
        const int4 z = make_int4(0, 0, 0, 0);
#pragma unroll
        for (int j = 0; j < 8; ++j) hz[t + 256 * j] = z;   // r8: j<8 = full 32KB
    }
    __syncthreads();

    unsigned int k[4][16];
    {
        float4 pr[4];
#pragma unroll
        for (int i = 0; i < 4; ++i) pr[i] = pb4[i * 256 + t];
#pragma unroll
        for (int i = 0; i < 16; ++i) {
            const float4 p = pr[i & 3];
            if (i < 12) pr[i & 3] = pb4[(i + 4) * 256 + t];
#pragma unroll
            for (int qi = 0; qi < 4; ++qi) {
                const float qp = __fadd_rn(__fadd_rn(__fmul_rn(qvv[qi].x, p.x),
                                                     __fmul_rn(qvv[qi].y, p.y)),
                                           __fmul_rn(qvv[qi].z, p.z));
                const float d2 = __fsub_rn(__fadd_rn(qvv[qi].w, p.w),
                                           __fmul_rn(2.0f, qp));
                unsigned int u = __float_as_uint(d2);
                u = (u & 0x80000000u) ? ~u : (u | 0x80000000u);
                k[qi][i] = u;
                atomicAdd(&histS[(qi << 11) | (u >> 21)], 1u);
            }
        }
    }
    __syncthreads();

    // level-0 scan, all 4 queries batched (one barrier set)
    unsigned int sq[4], vq[4];
#pragma unroll
    for (int qi = 0; qi < 4; ++qi) {
        unsigned int s = 0;
#pragma unroll
        for (int j = 0; j < 8; ++j) s += histS[(qi << 11) + t * 8 + j];
        unsigned int v = s;
#pragma unroll
        for (int off = 1; off < 64; off <<= 1) {
            const unsigned int o = __shfl_up(v, off);
            if (lane >= off) v += o;
        }
        if (lane == 63) wsumS[qi][w] = v;
        sq[qi] = s; vq[qi] = v;
    }
    __syncthreads();
#pragma unroll
    for (int qi = 0; qi < 4; ++qi) {
        unsigned int woff = 0;
#pragma unroll
        for (int i = 0; i < 4; ++i) if (i < w) woff += wsumS[qi][i];
        const unsigned int incl = woff + vq[qi], excl = incl - sq[qi];
        const unsigned int rank0 = KNN - 1;
        if (rank0 >= excl && rank0 < incl) {
            unsigned int e = excl;
            for (int j = 0; j < 8; ++j) {
                const unsigned int c = histS[(qi << 11) + t * 8 + j];
                if (rank0 < e + c) {
                    scS[qi][0] = (unsigned int)(t * 8 + j);
                    scS[qi][1] = rank0 - e;
                    scS[qi][2] = c;
                    break;
                }
                e += c;
            }
        }
    }
    __syncthreads();

    unsigned int prefq[4], rankq[4]; int shiftq[4];
#pragma unroll
    for (int qi = 0; qi < 4; ++qi) {
        prefq[qi] = scS[qi][0];
        rankq[qi] = scS[qi][1];
        shiftq[qi] = 21;
    }

    // rare fallback: threshold-bin population > 64 (block-uniform per query)
#pragma unroll
    for (int qi = 0; qi < 4; ++qi) {
        if (scS[qi][2] > 64) {
            for (int lvl = 1; lvl < 3; ++lvl) {
                const int nb  = (lvl == 1) ? 11 : 10;
                const int sh2 = (lvl == 1) ? 10 : 0;
                const unsigned int msk = (1u << nb) - 1u;
                const int g = (1 << nb) >> 8;
                for (int j = 0; j < g; ++j) histS[(qi << 11) + t * g + j] = 0u;
                __syncthreads();
#pragma unroll
                for (int i = 0; i < 16; ++i) {
                    const unsigned int u = k[qi][i];
                    if ((u >> (sh2 + nb)) == prefq[qi])
                        atomicAdd(&histS[(qi << 11) + ((u >> sh2) & msk)], 1u);
                }
                __syncthreads();
                unsigned int cnt[8];
                unsigned int s = 0;
                for (int j = 0; j < g; ++j) { cnt[j] = histS[(qi << 11) + t * g + j]; s += cnt[j]; }
                unsigned int v = s;
#pragma unroll
                for (int off = 1; off < 64; off <<= 1) {
                    const unsigned int o = __shfl_up(v, off);
                    if (lane >= off) v += o;
                }
                if (lane == 63) wsumS[qi][w] = v;
                __syncthreads();
                unsigned int woff = 0;
#pragma unroll
                for (int i2 = 0; i2 < 4; ++i2) if (i2 < w) woff += wsumS[qi][i2];
                const unsigned int incl = woff + v, excl = incl - s;
                const unsigned int r = rankq[qi];
                if (r >= excl && r < incl) {
                    unsigned int e = excl;
                    for (int j = 0; j < g; ++j) {
                        if (r < e + cnt[j]) {
                            scS[qi][0] = (prefq[qi] << nb) | (unsigned int)(t * g + j);
                            scS[qi][1] = r - e;
                            scS[qi][2] = cnt[j];
                            break;
                        }
                        e += cnt[j];
                    }
                }
                __syncthreads();
                prefq[qi] = scS[qi][0];
                rankq[qi] = scS[qi][1];
                shiftq[qi] = sh2;
                if (scS[qi][2] <= 64u || lvl == 2) break;
            }
        }
    }

    // compact: definite members + threshold-bin candidates (interleaved)
    if (t < 4) { scS[t][3] = 0u; scS[t][4] = 0u; }
    __syncthreads();
#pragma unroll
    for (int i = 0; i < 16; ++i) {
        const int n = i * 256 + t;
#pragma unroll
        for (int qi = 0; qi < 4; ++qi) {
            const unsigned int u = k[qi][i];
            const unsigned int hp = u >> shiftq[qi];
            if (hp < prefq[qi]) {
                const unsigned int slot = atomicAdd(&scS[qi][3], 1u);
                if (slot < KNN) nnLDS[qi][slot] = n;   // provably <32; bound anyway
            } else if (hp == prefq[qi]) {
                const unsigned int slot = atomicAdd(&scS[qi][4], 1u);
                if (slot < 64u) { ckeyS[qi][slot] = u; cidxS[qi][slot] = n; }
            }
        }
    }
    __syncthreads();

    // wave w resolves query w: exact (key, idx) lexicographic rank
    {
        const int candcnt = min((int)scS[w][4], 64);
        const int defcnt  = min((int)scS[w][3], KNN);
        const int rnk     = (int)scS[w][1];
        const unsigned int k_l = (lane < candcnt) ? ckeyS[w][lane] : 0xFFFFFFFFu;
        const int          i_l = (lane < candcnt) ? cidxS[w][lane] : 0x7FFFFFFF;
        int rk = 0;
        for (int j = 0; j < candcnt; ++j) {
            const unsigned int kj = __shfl(k_l, j);
            const int          ij = __shfl(i_l, j);
            if (kj < k_l || (kj == k_l && ij < i_l)) ++rk;
        }
        if (lane < candcnt && rk <= rnk && defcnt + rk < KNN)
            nnLDS[w][defcnt + rk] = i_l;
    }
    if (t < 4) {
        const float4 qv = (t == 0) ? qvv[0] : (t == 1) ? qvv[1] : (t == 2) ? qvv[2] : qvv[3];
        pos_q[(size_t)(qblk + t) * 3 + 0] = qv.x;
        pos_q[(size_t)(qblk + t) * 3 + 1] = qv.y;
        pos_q[(size_t)(qblk + t) * 3 + 2] = qv.z;
    }
    __syncthreads();   // nnLDS ready; hist region becomes frag region

    // ---------------- phase 2: MLP (r6-verified structure) ----------------
    const int q = qblk + w;
    const int wbase = w * 3072;
    const float4 qme = (w == 0) ? qvv[0] : (w == 1) ? qvv[1] : (w == 2) ? qvv[2] : qvv[3];

    {
        const int r = t >> 1, h = t & 1;
        const int kk = r & 31;
        const int n = nnLDS[w][kk];
        const int mt = kk >> 4, lrow = kk & 15;
        if (USE_F16) {
            const _Float16* frow = feat16 + ((size_t)b * NPTS + n) * CIN;
            if (h == 0) {                       // X cols 0..47: rel(3) + feat 0..44
                const float4 pv = pos4[(size_t)b * NPTS + n];
                half8 fa[6];
#pragma unroll
                for (int ii = 0; ii < 6; ++ii) fa[ii] = *(const half8*)(frow + ii * 8);
                float relf[3] = {pv.x - qme.x, pv.y - qme.y, pv.z - qme.z};
#pragma unroll
                for (int ci = 0; ci < 6; ++ci) {
                    half8 ph;
#pragma unroll
                    for (int jj = 0; jj < 8; ++jj) {
                        const int c = ci * 8 + jj;
                        ph[jj] = (c < 3) ? (_Float16)relf[c] : fa[(c - 3) >> 3][(c - 3) & 7];
                    }
                    const int kc = ci >> 2, qd = ci & 3;
                    *(half8*)&sh[wbase + ((kc * 2 + mt) * 64 + qd * 16 + lrow) * 8] = ph;
                }
            } else {                            // X cols 48..95: feat 45..63 + pad
                half8 fb[3];
#pragma unroll
                for (int ii = 0; ii < 3; ++ii) fb[ii] = *(const half8*)(frow + 40 + ii * 8);
#pragma unroll
                for (int ci = 6; ci < 12; ++ci) {
                    half8 ph;
#pragma unroll
                    for (int jj = 0; jj < 8; ++jj) {
                        const int c = ci * 8 + jj;
                        _Float16 v = (_Float16)0.0f;
                        if (c < 67) { const int f = c - 43; v = fb[f >> 3][f & 7]; }
                        ph[jj] = v;
                    }
                    const int kc = ci >> 2, qd = ci & 3;
                    *(half8*)&sh[wbase + ((kc * 2 + mt) * 64 + qd * 16 + lrow) * 8] = ph;
                }
            }
        } else {                                // fp32 fallback (r6 gather)
            const float4* f4 = (const float4*)(feat + ((size_t)b * NPTS + n) * CIN);
            if (h == 0) {
                const float4 pv = pos4[(size_t)b * NPTS + n];
                float4 ff[12];
#pragma unroll
                for (int ii = 0; ii < 12; ++ii) ff[ii] = f4[ii];
                float relf[3] = {pv.x - qme.x, pv.y - qme.y, pv.z - qme.z};
#pragma unroll
                for (int ci = 0; ci < 6; ++ci) {
                    half8 ph;
#pragma unroll
                    for (int jj = 0; jj < 8; ++jj) {
                        const int c = ci * 8 + jj;
                        float v;
                        if (c < 3) v = relf[c];
                        else {
                            const int fc = c - 3;
                            const float4 vv = ff[fc >> 2];
                            v = ((fc & 3) == 0) ? vv.x : ((fc & 3) == 1) ? vv.y
                              : ((fc & 3) == 2) ? vv.z : vv.w;
                        }
                        ph[jj] = (_Float16)v;
                    }
                    const int kc = ci >> 2, qd = ci & 3;
                    *(half8*)&sh[wbase + ((kc * 2 + mt) * 64 + qd * 16 + lrow) * 8] = ph;
                }
            } else {
                float4 ff[5];
#pragma unroll
                for (int ii = 0; ii < 5; ++ii) ff[ii] = f4[11 + ii];
#pragma unroll
                for (int ci = 6; ci < 12; ++ci) {
                    half8 ph;
#pragma unroll
                    for (int jj = 0; jj < 8; ++jj) {
                        const int c = ci * 8 + jj;
                        float v = 0.0f;
                        if (c < 67) {
                            const int fc = c - 3;
                            const float4 vv = ff[(fc >> 2) - 11];
                            v = ((fc & 3) == 0) ? vv.x : ((fc & 3) == 1) ? vv.y
                              : ((fc & 3) == 2) ? vv.z : vv.w;
                        }
                        ph[jj] = (_Float16)v;
                    }
                    const int kc = ci >> 2, qd = ci & 3;
                    *(half8*)&sh[wbase + ((kc * 2 + mt) * 64 + qd * 16 + lrow) * 8] = ph;
                }
            }
        }
    }
    // no barrier: frag region is wave-private, DS pipe in-order per wave

    const int col = lane & 15, quad = lane >> 4;

    half8 af[3][2];
#pragma unroll
    for (int kc = 0; kc < 3; ++kc)
#pragma unroll
        for (int mt = 0; mt < 2; ++mt)
            af[kc][mt] = *(const half8*)&sh[wbase + ((kc * 2 + mt) * 64 + lane) * 8];

    half8 w1f[3][4];
#pragma unroll
    for (int kc = 0; kc < 3; ++kc)
#pragma unroll
        for (int nt = 0; nt < 4; ++nt)
            w1f[kc][nt] = *(const half8*)(wf + (size_t)((kc * 4 + nt) * 64 + lane) * 8);

#pragma unroll
    for (int nt = 0; nt < 4; ++nt) {
        const float bv = b1[nt * 16 + col];
        floatx4 acc0 = {bv, bv, bv, bv}, acc1 = acc0;
#pragma unroll
        for (int kc = 0; kc < 3; ++kc) {
            acc0 = __builtin_amdgcn_mfma_f32_16x16x32_f16(af[kc][0], w1f[kc][nt], acc0, 0, 0, 0);
            acc1 = __builtin_amdgcn_mfma_f32_16x16x32_f16(af[kc][1], w1f[kc][nt], acc1, 0, 0, 0);
        }
        const int kc2 = nt >> 1;
        const int quad2 = (((nt & 1) * 16) + col) >> 3;
        const int j2 = col & 7;
#pragma unroll
        for (int mt = 0; mt < 2; ++mt) {
            const floatx4 a = mt ? acc1 : acc0;
#pragma unroll
            for (int reg = 0; reg < 4; ++reg) {
                const int row = quad * 4 + reg;
                sh[wbase + ((kc2 * 2 + mt) * 64 + quad2 * 16 + row) * 8 + j2] =
                    (_Float16)fmaxf(a[reg], 0.0f);
            }
        }
    }

    half8 a2[2][2];
#pragma unroll
    for (int kc2 = 0; kc2 < 2; ++kc2)
#pragma unroll
        for (int mt = 0; mt < 2; ++mt)
            a2[kc2][mt] = *(const half8*)&sh[wbase + ((kc2 * 2 + mt) * 64 + lane) * 8];

    half8 w2f[2][8];
#pragma unroll
    for (int kc2 = 0; kc2 < 2; ++kc2)
#pragma unroll
        for (int nt2 = 0; nt2 < 8; ++nt2)
            w2f[kc2][nt2] = *(const half8*)(wf + (size_t)W1F_HALVES
                                            + (size_t)((kc2 * 8 + nt2) * 64 + lane) * 8);

    float* oq = out + (size_t)q * H2D;
#pragma unroll
    for (int nt2 = 0; nt2 < 8; ++nt2) {
        const float bv = b2[nt2 * 16 + col];
        floatx4 acc0 = {bv, bv, bv, bv}, acc1 = acc0;
#pragma unroll
        for (int kc2 = 0; kc2 < 2; ++kc2) {
            acc0 = __builtin_amdgcn_mfma_f32_16x16x32_f16(a2[kc2][0], w2f[kc2][nt2], acc0, 0, 0, 0);
            acc1 = __builtin_amdgcn_mfma_f32_16x16x32_f16(a2[kc2][1], w2f[kc2][nt2], acc1, 0, 0, 0);
        }
        float mm = fmaxf(fmaxf(fmaxf(acc0[0], acc0[1]), fmaxf(acc0[2], acc0[3])),
                         fmaxf(fmaxf(acc1[0], acc1[1]), fmaxf(acc1[2], acc1[3])));
        mm = fmaxf(mm, 0.0f);
        mm = fmaxf(mm, __shfl_xor(mm, 16));
        mm = fmaxf(mm, __shfl_xor(mm, 32));
        if (lane < 16) oq[nt2 * 16 + lane] = mm;
    }
}

extern "C" void kernel_launch(void* const* d_in, const int* in_sizes, int n_in,
                              void* d_out, int out_size, void* d_ws, size_t ws_size,
                              hipStream_t stream)
{
    const float* pos  = (const float*)d_in[0];
    const float* feat = (const float*)d_in[1];
    const float* W1   = (const float*)d_in[2];
    const float* b1   = (const float*)d_in[3];
    const float* W2   = (const float*)d_in[4];
    const float* b2   = (const float*)d_in[5];
    const int*   idx  = (const int*)d_in[6];   // int64 delivered as int32

    float* pos_q = (float*)d_out;
    float* out   = (float*)d_out + (size_t)BATCH * MQ * 3;
    _Float16* wf  = (_Float16*)d_ws;
    float4*   p4  = (float4*)((char*)d_ws + WS_P4_OFF);
    _Float16* f16 = (_Float16*)((char*)d_ws + WS_F16_OFF);

    const int use_f16 = (ws_size >= WS_NEED) ? 1 : 0;
    const int prep_threads = 1792 + BATCH * NPTS + (use_f16 ? BATCH * NPTS * 8 : 0);
    wprep_kernel<<<(prep_threads + 255) / 256, 256, 0, stream>>>(
        W1, W2, pos, feat, wf, p4, f16, use_f16);
    if (use_f16)
        fused_kernel<1><<<BATCH * MQ / 4, 256, 0, stream>>>(
            p4, feat, f16, idx, b1, b2, wf, pos_q, out);
    else
        fused_kernel<0><<<BATCH * MQ / 4, 256, 0, stream>>>(
            p4, feat, f16, idx, b1, b2, wf, pos_q, out);
}